// Round 2
// baseline (353.667 us; speedup 1.0000x reference)
//
#include <hip/hip_runtime.h>
#include <hip/hip_bf16.h>

// Llama4 Vision Attention, MI355X bf16-MFMA pipeline.
// B=16 S=576 E=1408 H=16 D=88 (pad 96). fp32 in/out, bf16 internal compute.

typedef unsigned short UST;
typedef __attribute__((ext_vector_type(8))) __bf16 bf16x8;
typedef __attribute__((ext_vector_type(4))) float f32x4;
typedef __attribute__((ext_vector_type(8))) UST us8;
typedef __attribute__((ext_vector_type(4))) UST us4;

typedef __attribute__((address_space(3))) unsigned int lds_u32;
typedef const __attribute__((address_space(1))) unsigned int glob_u32;

static __device__ __forceinline__ float bf2f(UST u){
  unsigned int x = ((unsigned int)u) << 16;
  return __builtin_bit_cast(float, x);
}
static __device__ __forceinline__ UST f2bf(float f){
  unsigned int x = __builtin_bit_cast(unsigned int, f);
  x += 0x7fffu + ((x >> 16) & 1u);   // RN-even; inputs finite
  return (UST)(x >> 16);
}

// ---------------- RoPE tables: cos/sin [576][44], f64 math to match numpy ----
__global__ void k_tables(float* __restrict__ cosT, float* __restrict__ sinT){
  int s = blockIdx.x;
  int p = threadIdx.x;
  if (p >= 44) return;
  int tt = p % 22;
  double comp = (p < 22) ? (double)(s % 24 + 1) : (double)(s / 24 + 1);
  double a = comp * pow(10000.0, -(double)tt / 22.0);
  cosT[s*44 + p] = (float)cos(a);
  sinT[s*44 + p] = (float)sin(a);
}

// ---------------- fp32 -> bf16 cast (vectorized) ----------------------------
__global__ void k_cvt(const float* __restrict__ in, UST* __restrict__ out, int n4){
  int i = blockIdx.x * 256 + threadIdx.x;
  if (i >= n4) return;
  float4 v = ((const float4*)in)[i];
  us4 o; o[0]=f2bf(v.x); o[1]=f2bf(v.y); o[2]=f2bf(v.z); o[3]=f2bf(v.w);
  *(us4*)(out + 4*(size_t)i) = o;
}

// ---------------- fp32 [K][N] -> bf16 [N][K] transpose-convert --------------
__global__ void k_cvt_t(const float* __restrict__ W, UST* __restrict__ Bt, int K, int N){
  __shared__ __align__(16) UST tl[64][70];  // stride 70: odd dword stride -> low conflict
  int kt = blockIdx.x, nt = blockIdx.y;
  int t = threadIdx.x;
  int k = t >> 2, u = t & 3;
  const float* src = W + (size_t)(kt*64 + k)*N + nt*64 + u*16;
#pragma unroll
  for (int i = 0; i < 4; ++i){
    float4 v = *(const float4*)(src + 4*i);
    UST* d = &tl[k][u*16 + 4*i];
    d[0]=f2bf(v.x); d[1]=f2bf(v.y); d[2]=f2bf(v.z); d[3]=f2bf(v.w);
  }
  __syncthreads();
  int n = t >> 2;
  UST* dst = Bt + (size_t)(nt*64 + n)*K + kt*64 + u*16;
#pragma unroll
  for (int i = 0; i < 2; ++i){
    us8 o;
#pragma unroll
    for (int j = 0; j < 8; ++j) o[j] = tl[u*16 + 8*i + j][n];
    *(us8*)(dst + 8*i) = o;
  }
}

// ---------------- bf16 GEMM: C[M][N] = A[M][K] @ Bt[N][K]^T + bias ----------
// m97 structure: 128x128 tile, BK=64, global_load_lds w/ pre-swizzled source,
// XOR-swizzled ds_read_b128 frags, 2-phase prefetch, 1 barrier/iter.
template<bool OUT_BF16>
__global__ __launch_bounds__(256, 2) void k_gemm(
    const UST* __restrict__ A, const UST* __restrict__ Bt,
    const float* __restrict__ bias, void* __restrict__ Cout,
    int M, int N, int K)
{
  __shared__ __align__(16) UST lA[2][128][64];
  __shared__ __align__(16) UST lB[2][128][64];
  const int t = threadIdx.x;
  const int bm = blockIdx.x, bn = blockIdx.y;
  const int wave = t >> 6, lane = t & 63;
  const int lm = lane & 15, g = lane >> 4;
  const int wr = (wave >> 1) << 6, wc = (wave & 1) << 6;
  // staging: wave stages rows [32w,32w+32) of both tiles; lane covers 16B.
  const int lrow = lane >> 3;                       // 0..7 within 8-row chunk
  const int lcol = (((lane & 7) ^ lrow) << 3);      // pre-swizzled source col
  const UST* Ag = A  + (size_t)(bm*128 + wave*32 + lrow)*K + lcol;
  const UST* Bg = Bt + (size_t)(bn*128 + wave*32 + lrow)*K + lcol;

  f32x4 zero = {0.f,0.f,0.f,0.f};
  f32x4 acc[4][4];
#pragma unroll
  for (int i=0;i<4;++i)
#pragma unroll
    for (int j=0;j<4;++j) acc[i][j] = zero;

  const int nkt = K >> 6;
  auto stage = [&](int kt, int buf){
#pragma unroll
    for (int c = 0; c < 4; ++c){
      __builtin_amdgcn_global_load_lds((glob_u32*)(Ag + (size_t)kt*64 + (size_t)(8*c)*K),
                                       (lds_u32*)(&lA[buf][wave*32 + 8*c][0]), 16, 0, 0);
      __builtin_amdgcn_global_load_lds((glob_u32*)(Bg + (size_t)kt*64 + (size_t)(8*c)*K),
                                       (lds_u32*)(&lB[buf][wave*32 + 8*c][0]), 16, 0, 0);
    }
  };

  stage(0, 0);
  __syncthreads();
  const int swz = (lm & 7) << 3;

  for (int kt = 0; kt < nkt; ++kt){
    const int cur = kt & 1;
    if (kt + 1 < nkt) stage(kt + 1, cur ^ 1);
#pragma unroll
    for (int ks = 0; ks < 2; ++ks){
      bf16x8 af[4], bfv[4];
      const int cb = (ks*32 + g*8) ^ swz;
#pragma unroll
      for (int mf = 0; mf < 4; ++mf)
        af[mf] = __builtin_bit_cast(bf16x8, *(const us8*)&lA[cur][wr + mf*16 + lm][cb]);
#pragma unroll
      for (int nf = 0; nf < 4; ++nf)
        bfv[nf] = __builtin_bit_cast(bf16x8, *(const us8*)&lB[cur][wc + nf*16 + lm][cb]);
#pragma unroll
      for (int mf = 0; mf < 4; ++mf)
#pragma unroll
        for (int nf = 0; nf < 4; ++nf)
          acc[mf][nf] = __builtin_amdgcn_mfma_f32_16x16x32_bf16(af[mf], bfv[nf], acc[mf][nf], 0, 0, 0);
    }
    __syncthreads();   // drains vmcnt -> next buffer ready; protects buffer reuse
  }

#pragma unroll
  for (int nf = 0; nf < 4; ++nf){
    const int col = bn*128 + wc + nf*16 + lm;
    const float bv = bias[col];
#pragma unroll
    for (int mf = 0; mf < 4; ++mf){
      const size_t rb = (size_t)(bm*128 + wr + mf*16 + g*4);
#pragma unroll
      for (int r = 0; r < 4; ++r){
        float v = acc[mf][nf][r] + bv;
        if (OUT_BF16) ((UST*)Cout)[(rb + r)*(size_t)N + col] = f2bf(v);
        else          ((float*)Cout)[(rb + r)*(size_t)N + col] = v;
      }
    }
  }
}

// ---------------- RoPE + pack: qkv[9216][4224] -> qa/ka [bh][s][96], vt [bh][96][576]
// LDS swizzle: rows are 11 chunks of 8; only chunks 0..7 are XOR-permuted
// (closed under ^sw), chunks 8..10 stay identity. Same map on write & read.
__global__ __launch_bounds__(256) void k_rope(
    const UST* __restrict__ qkv, const float* __restrict__ cosT, const float* __restrict__ sinT,
    UST* __restrict__ qa, UST* __restrict__ ka, UST* __restrict__ vt)
{
  __shared__ float lc[64][44], lsn[64][44];
  __shared__ __align__(16) UST sl[64][104];
  const int bh = blockIdx.x, st = blockIdx.y;
  const int b = bh >> 4, h = bh & 15;
  const int t = threadIdx.x;
  const int s0 = st * 64;
  for (int c = t; c < 64*44; c += 256){
    int s = c / 44, p = c % 44;
    lc[s][p]  = cosT[(s0+s)*44 + p];
    lsn[s][p] = sinT[(s0+s)*44 + p];
  }
  const size_t rowbase = ((size_t)(b*576 + s0))*4224 + h*88;

  for (int j = 0; j < 2; ++j){
    __syncthreads();
    for (int c = t; c < 704; c += 256){
      int r = c / 11, ch = c % 11;
      int chS = (ch < 8) ? (ch ^ ((r>>3)&7)) : ch;
      *(uint4*)&sl[r][chS*8] = *(const uint4*)(qkv + rowbase + (size_t)r*4224 + j*1408 + ch*8);
    }
    __syncthreads();
    const int s = t >> 2, u = t & 3;
    const size_t obase = ((size_t)bh*576 + s0 + s)*96;
    UST* outp = (j == 0) ? qa : ka;
    const float sc = (j == 0) ? 0.10660035817780521f : 1.0f;  // 88^-0.5 folded into q
    const int sw3 = (s>>3)&7;
#pragma unroll
    for (int i = 0; i < 11; ++i){
      int p = u*11 + i;
      int e = 2*p;
      int chunk = e >> 3;
      int pos = ((chunk < 8) ? (chunk ^ sw3) : chunk)*8 + (e & 7);
      float x0 = bf2f(sl[s][pos]);
      float x1 = bf2f(sl[s][pos+1]);   // e even -> pos+1 stays in chunk
      float cv = lc[s][p], sv = lsn[s][p];
      float o0 = (x0*cv - x1*sv)*sc;
      float o1 = (x0*sv + x1*cv)*sc;
      unsigned int pk = (unsigned int)f2bf(o0) | ((unsigned int)f2bf(o1) << 16);
      *(unsigned int*)(outp + obase + 2*p) = pk;
    }
    if (u == 3){ uint4 z = {0,0,0,0}; *(uint4*)(outp + obase + 88) = z; }  // zero-pad d 88..95
  }

  // V: stage slice then write transposed vt[bh][96][576] (rows 88..95 zero)
  __syncthreads();
  for (int c = t; c < 704; c += 256){
    int r = c / 11, ch = c % 11;
    int chS = (ch < 8) ? (ch ^ ((r>>3)&7)) : ch;
    *(uint4*)&sl[r][chS*8] = *(const uint4*)(qkv + rowbase + (size_t)r*4224 + 2*1408 + ch*8);
  }
  __syncthreads();
  for (int c = t; c < 768; c += 256){
    int d = c >> 3, ch = c & 7;
    us8 o;
    if (d < 88){
      int chunk = d >> 3;
#pragma unroll
      for (int jj = 0; jj < 8; ++jj){
        int r = ch*8 + jj;        // r>>3 == ch
        int pos = ((chunk < 8) ? (chunk ^ (ch & 7)) : chunk)*8 + (d & 7);
        o[jj] = sl[r][pos];
      }
    } else {
#pragma unroll
      for (int jj = 0; jj < 8; ++jj) o[jj] = 0;
    }
    *(us8*)(vt + ((size_t)bh*96 + d)*576 + s0 + ch*8) = o;
  }
}

// ---------------- flash attention: per (bh, qtile64); 4 waves x 16 q-rows ---
__global__ __launch_bounds__(256, 2) void k_attn(
    const UST* __restrict__ qa, const UST* __restrict__ ka,
    const UST* __restrict__ vt, UST* __restrict__ outp)
{
  __shared__ __align__(16) UST lK[64][104];   // K tile [kv][d]
  __shared__ __align__(16) UST lV[96][72];    // V^T tile [d][kv]
  __shared__ __align__(16) UST lP[4][16][72]; // per-wave P [q][kv]
  const int bh = blockIdx.x, qt = blockIdx.y;
  const int t = threadIdx.x, wave = t >> 6, lane = t & 63;
  const int lm = lane & 15, g = lane >> 4;
  const int h = bh & 15, b = bh >> 4;

  bf16x8 qf[3];
  {
    const UST* qp = qa + ((size_t)bh*576 + qt*64 + wave*16 + lm)*96 + g*8;
#pragma unroll
    for (int ks = 0; ks < 3; ++ks) qf[ks] = __builtin_bit_cast(bf16x8, *(const us8*)(qp + ks*32));
  }
  f32x4 zero = {0.f,0.f,0.f,0.f};
  f32x4 acc[6];
#pragma unroll
  for (int i = 0; i < 6; ++i) acc[i] = zero;
  float mrun[4], lrun[4];
#pragma unroll
  for (int r = 0; r < 4; ++r){ mrun[r] = -1e30f; lrun[r] = 0.f; }

  const UST* kbase = ka + (size_t)bh*576*96;
  const UST* vbase = vt + (size_t)bh*96*576;

  for (int kvt = 0; kvt < 9; ++kvt){
    { // stage K [64][96]
      int r = t >> 2, u = t & 3;
      const UST* src = kbase + (size_t)(kvt*64 + r)*96 + u*24;
#pragma unroll
      for (int i = 0; i < 3; ++i)
        *(uint4*)&lK[r][u*24 + i*8] = *(const uint4*)(src + i*8);
    }
    if (t < 192){ // stage V^T [96][64]
      int d = t >> 1, hf = t & 1;
      const UST* src = vbase + (size_t)d*576 + kvt*64 + hf*32;
#pragma unroll
      for (int i = 0; i < 4; ++i)
        *(uint4*)&lV[d][hf*32 + i*8] = *(const uint4*)(src + i*8);
    }
    __syncthreads();

    // QK^T -> sc[nf][r]: S[q = w*16 + 4g+r][kv = nf*16 + lm]
    f32x4 sc[4];
#pragma unroll
    for (int i = 0; i < 4; ++i) sc[i] = zero;
#pragma unroll
    for (int ks = 0; ks < 3; ++ks){
#pragma unroll
      for (int nf = 0; nf < 4; ++nf){
        bf16x8 kf = __builtin_bit_cast(bf16x8, *(const us8*)&lK[nf*16 + lm][ks*32 + g*8]);
        sc[nf] = __builtin_amdgcn_mfma_f32_16x16x32_bf16(qf[ks], kf, sc[nf], 0, 0, 0);
      }
    }
    // online softmax (rows 4g+r; reduce over lm lanes + nf frags)
    float mx[4];
#pragma unroll
    for (int r = 0; r < 4; ++r)
      mx[r] = fmaxf(fmaxf(sc[0][r], sc[1][r]), fmaxf(sc[2][r], sc[3][r]));
#pragma unroll
    for (int m = 1; m <= 8; m <<= 1)
#pragma unroll
      for (int r = 0; r < 4; ++r) mx[r] = fmaxf(mx[r], __shfl_xor(mx[r], m, 64));
    float al[4];
#pragma unroll
    for (int r = 0; r < 4; ++r){
      float mnew = fmaxf(mrun[r], mx[r]);
      float corr = __expf(mrun[r] - mnew);
      mrun[r] = mnew;
      lrun[r] *= corr;
      float ls = 0.f;
#pragma unroll
      for (int nf = 0; nf < 4; ++nf){
        float p = __expf(sc[nf][r] - mnew);
        sc[nf][r] = p;
        ls += p;
      }
#pragma unroll
      for (int df = 0; df < 6; ++df) acc[df][r] *= corr;
      al[r] = ls;
    }
#pragma unroll
    for (int m = 1; m <= 8; m <<= 1)
#pragma unroll
      for (int r = 0; r < 4; ++r) al[r] += __shfl_xor(al[r], m, 64);
#pragma unroll
    for (int r = 0; r < 4; ++r) lrun[r] += al[r];

    // P -> LDS (wave-local), read back as A-frags
#pragma unroll
    for (int nf = 0; nf < 4; ++nf)
#pragma unroll
      for (int r = 0; r < 4; ++r)
        lP[wave][4*g + r][nf*16 + lm] = f2bf(sc[nf][r]);

    bf16x8 pa[2];
#pragma unroll
    for (int ks2 = 0; ks2 < 2; ++ks2)
      pa[ks2] = __builtin_bit_cast(bf16x8, *(const us8*)&lP[wave][lm][ks2*32 + g*8]);
#pragma unroll
    for (int ks2 = 0; ks2 < 2; ++ks2)
#pragma unroll
      for (int df = 0; df < 6; ++df){
        bf16x8 vf = __builtin_bit_cast(bf16x8, *(const us8*)&lV[df*16 + lm][ks2*32 + g*8]);
        acc[df] = __builtin_amdgcn_mfma_f32_16x16x32_bf16(pa[ks2], vf, acc[df], 0, 0, 0);
      }
    __syncthreads();
  }

  float inv[4];
#pragma unroll
  for (int r = 0; r < 4; ++r) inv[r] = 1.f / lrun[r];
  const size_t rowt = (size_t)b*576 + qt*64 + wave*16;
#pragma unroll
  for (int df = 0; df < 6; ++df){
    int d = df*16 + lm;
    if (d < 88){
#pragma unroll
      for (int r = 0; r < 4; ++r)
        outp[(rowt + 4*g + r)*1408 + h*88 + d] = f2bf(acc[df][r] * inv[r]);
    }
  }
}

// ---------------- launch ----------------------------------------------------
extern "C" void kernel_launch(void* const* d_in, const int* in_sizes, int n_in,
                              void* d_out, int out_size, void* d_ws, size_t ws_size,
                              hipStream_t stream)
{
  (void)in_sizes; (void)n_in; (void)out_size; (void)ws_size;
  const float* hs   = (const float*)d_in[0];
  const float* wqkv = (const float*)d_in[1];
  const float* bqkv = (const float*)d_in[2];
  const float* wo   = (const float*)d_in[3];
  const float* bo   = (const float*)d_in[4];
  float* out = (float*)d_out;

  char* w = (char*)d_ws;                       // needs ~195.3 MiB
  UST* A_bf   = (UST*)(w);                     // 25,952,256  (hidden bf16; reused as attn out)
  UST* Bt1    = (UST*)(w + 25952256);          // 11,894,784  (w_qkv^T bf16)
  UST* Bt2    = (UST*)(w + 37847040);          //  3,964,928  (w_o^T bf16)
  UST* qkvb   = (UST*)(w + 41811968);          // 77,856,768  (qkv bf16)
  UST* qa     = (UST*)(w + 119668736);         // 28,311,552
  UST* ka     = (UST*)(w + 147980288);         // 28,311,552
  UST* vt     = (UST*)(w + 176291840);         // 28,311,552
  float* cosT = (float*)(w + 204603392);       //    101,376
  float* sinT = (float*)(w + 204704768);       //    101,376

  k_tables<<<576, 64, 0, stream>>>(cosT, sinT);
  k_cvt<<<12672, 256, 0, stream>>>(hs, A_bf, 3244032);
  k_cvt_t<<<dim3(22, 66), 256, 0, stream>>>(wqkv, Bt1, 1408, 4224);
  k_cvt_t<<<dim3(22, 22), 256, 0, stream>>>(wo, Bt2, 1408, 1408);
  k_gemm<true ><<<dim3(72, 33), 256, 0, stream>>>(A_bf, Bt1, bqkv, qkvb, 9216, 4224, 1408);
  k_rope<<<dim3(256, 9), 256, 0, stream>>>(qkvb, cosT, sinT, qa, ka, vt);
  k_attn<<<dim3(256, 9), 256, 0, stream>>>(qa, ka, vt, A_bf);
  k_gemm<false><<<dim3(72, 11), 256, 0, stream>>>(A_bf, Bt2, bo, out, 9216, 1408, 1408);
}